// Round 6
// baseline (1985.717 us; speedup 1.0000x reference)
//
#include <hip/hip_runtime.h>
#include <hip/hip_bf16.h>
#include <stdint.h>

#define N_NODES 100000
#define N_EDGES 3200000
#define ALPHA   0.1f
#define EB      256      // edges per propA chunk
#define NCHUNK  (N_EDGES / EB)   // 12500
#define HALFN   800000   // N * 8 floats per class-half

typedef __attribute__((ext_vector_type(8))) short v8s;   // 8 x bf16
typedef __attribute__((ext_vector_type(4))) float f32x4; // MFMA acc

__device__ __forceinline__ uint32_t bf16_rne(float f) {
    uint32_t u = __float_as_uint(f);
    return (u + 0x7FFFu + ((u >> 16) & 1u)) >> 16;
}
__device__ __forceinline__ float bf16_f32(uint32_t b) { return __uint_as_float(b << 16); }

// ---------------------------------------------------------------------------
// W1 [256][512] fp32 -> A-fragment-ordered hi/lo bf16 chunks in global.
// ---------------------------------------------------------------------------
__global__ __launch_bounds__(256) void w1_frag_kernel(
    const float* __restrict__ W1, uint4* __restrict__ W1f)
{
    int tid = blockIdx.x * 256 + threadIdx.x;   // 16384
    int ks = tid >> 10, T = (tid >> 6) & 15, l = tid & 63;
    int row = T * 16 + (l & 15);
    int kb  = ks * 32 + (l >> 4) * 8;
    const float* src = W1 + (size_t)row * 512 + kb;
    float4 f0 = *(const float4*)(src);
    float4 f1 = *(const float4*)(src + 4);
    float f[8] = {f0.x, f0.y, f0.z, f0.w, f1.x, f1.y, f1.z, f1.w};
    uint32_t hi[8], lo[8];
#pragma unroll
    for (int j = 0; j < 8; ++j) {
        hi[j] = bf16_rne(f[j]);
        lo[j] = bf16_rne(f[j] - bf16_f32(hi[j]));
    }
    uint4 H = make_uint4(hi[0] | (hi[1] << 16), hi[2] | (hi[3] << 16),
                         hi[4] | (hi[5] << 16), hi[6] | (hi[7] << 16));
    uint4 L = make_uint4(lo[0] | (lo[1] << 16), lo[2] | (lo[3] << 16),
                         lo[4] | (lo[5] << 16), lo[6] | (lo[7] << 16));
    size_t base = ((size_t)(ks * 2) * 16 + T) * 64 + l;
    W1f[base]        = H;
    W1f[base + 1024] = L;   // p=1 plane
}

// ---------------------------------------------------------------------------
// MLP via MFMA bf16 hi/lo split. Epilogue writes class-half arrays:
// hA/hB [N,8] and zsA/zsB = dinv*h halves (initial propagation state).
// ---------------------------------------------------------------------------
__global__ __launch_bounds__(256, 4) void mlp_kernel(
    const float* __restrict__ x, const uint4* __restrict__ W1f,
    const float* __restrict__ b1, const float* __restrict__ W2,
    const float* __restrict__ b2, const float* __restrict__ dinv,
    float* __restrict__ hA, float* __restrict__ hB,
    float* __restrict__ zsA, float* __restrict__ zsB, int n)
{
    __shared__ __align__(16) char smem[33280];
    char*  xs   = smem;                    // K-loop: hi plane 4096 + lo plane 4096
    float* W2s  = (float*)smem;            // epilogue: [16][260] = 16640 B
    float* part = (float*)(smem + 16640);  // epilogue: [4][64][16] = 16384 B

    const int tid = threadIdx.x;
    const int w = tid >> 6, l = tid & 63;
    const int l15 = l & 15, q = l >> 4;
    const int row0 = blockIdx.x * 64;

    const int s_l15 = tid & 15;
    const int s_seg = (tid >> 4) & 3;
    const int s_u   = tid >> 6;
    const int s_grow = row0 + s_u * 16 + s_l15;

    f32x4 acc[4][4];
#pragma unroll
    for (int mt = 0; mt < 4; ++mt)
#pragma unroll
        for (int nt = 0; nt < 4; ++nt) acc[mt][nt] = (f32x4){0.f, 0.f, 0.f, 0.f};

    for (int ks = 0; ks < 16; ++ks) {
        uint4 aHu[4], aLu[4];
#pragma unroll
        for (int mt = 0; mt < 4; ++mt) {
            size_t cidx = ((size_t)(ks * 2) * 16 + (w * 4 + mt)) * 64 + l;
            aHu[mt] = W1f[cidx];
            aLu[mt] = W1f[cidx + 1024];
        }
        float4 f0 = make_float4(0.f, 0.f, 0.f, 0.f), f1 = f0;
        if (s_grow < n) {
            const float* xp = x + (size_t)s_grow * 512 + ks * 32 + s_seg * 8;
            f0 = *(const float4*)(xp);
            f1 = *(const float4*)(xp + 4);
        }
        float f[8] = {f0.x, f0.y, f0.z, f0.w, f1.x, f1.y, f1.z, f1.w};
        uint32_t hi[8], lo[8];
#pragma unroll
        for (int j = 0; j < 8; ++j) {
            hi[j] = bf16_rne(f[j]);
            lo[j] = bf16_rne(f[j] - bf16_f32(hi[j]));
        }
        uint4 H = make_uint4(hi[0] | (hi[1] << 16), hi[2] | (hi[3] << 16),
                             hi[4] | (hi[5] << 16), hi[6] | (hi[7] << 16));
        uint4 L = make_uint4(lo[0] | (lo[1] << 16), lo[2] | (lo[3] << 16),
                             lo[4] | (lo[5] << 16), lo[6] | (lo[7] << 16));
        __syncthreads();
        *(uint4*)(xs +        s_u * 1024 + (s_seg * 16 + s_l15) * 16) = H;
        *(uint4*)(xs + 4096 + s_u * 1024 + (s_seg * 16 + s_l15) * 16) = L;
        __syncthreads();

        v8s bH[4], bL[4];
#pragma unroll
        for (int nt = 0; nt < 4; ++nt) {
            bH[nt] = *(v8s*)(xs +        nt * 1024 + l * 16);
            bL[nt] = *(v8s*)(xs + 4096 + nt * 1024 + l * 16);
        }
#pragma unroll
        for (int mt = 0; mt < 4; ++mt) {
            v8s aH = *(v8s*)&aHu[mt];
            v8s aL = *(v8s*)&aLu[mt];
#pragma unroll
            for (int nt = 0; nt < 4; ++nt) {
                f32x4 c = acc[mt][nt];
                c = __builtin_amdgcn_mfma_f32_16x16x32_bf16(aH, bH[nt], c, 0, 0, 0);
                c = __builtin_amdgcn_mfma_f32_16x16x32_bf16(aH, bL[nt], c, 0, 0, 0);
                c = __builtin_amdgcn_mfma_f32_16x16x32_bf16(aL, bH[nt], c, 0, 0, 0);
                acc[mt][nt] = c;
            }
        }
    }

#pragma unroll
    for (int mt = 0; mt < 4; ++mt) {
        float4 bv = *(const float4*)(b1 + w * 64 + mt * 16 + q * 4);
#pragma unroll
        for (int nt = 0; nt < 4; ++nt) {
            acc[mt][nt][0] = fmaxf(acc[mt][nt][0] + bv.x, 0.f);
            acc[mt][nt][1] = fmaxf(acc[mt][nt][1] + bv.y, 0.f);
            acc[mt][nt][2] = fmaxf(acc[mt][nt][2] + bv.z, 0.f);
            acc[mt][nt][3] = fmaxf(acc[mt][nt][3] + bv.w, 0.f);
        }
    }

    __syncthreads();
    {
        int c = tid >> 4, k16 = (tid & 15) * 16;
#pragma unroll
        for (int i = 0; i < 4; ++i)
            *(float4*)(W2s + c * 260 + k16 + i * 4) =
                *(const float4*)(W2 + c * 256 + k16 + i * 4);
    }
    __syncthreads();

#pragma unroll
    for (int c4 = 0; c4 < 4; ++c4) {
        float p2[4][4];
#pragma unroll
        for (int nt = 0; nt < 4; ++nt)
#pragma unroll
            for (int cc = 0; cc < 4; ++cc) p2[nt][cc] = 0.f;
#pragma unroll
        for (int mt = 0; mt < 4; ++mt)
#pragma unroll
            for (int cc = 0; cc < 4; ++cc) {
                float4 wv = *(float4*)(W2s + (c4 * 4 + cc) * 260 + w * 64 + mt * 16 + q * 4);
#pragma unroll
                for (int nt = 0; nt < 4; ++nt)
                    p2[nt][cc] += acc[mt][nt][0] * wv.x + acc[mt][nt][1] * wv.y +
                                  acc[mt][nt][2] * wv.z + acc[mt][nt][3] * wv.w;
            }
#pragma unroll
        for (int nt = 0; nt < 4; ++nt)
#pragma unroll
            for (int cc = 0; cc < 4; ++cc) {
                p2[nt][cc] += __shfl_xor(p2[nt][cc], 16);
                p2[nt][cc] += __shfl_xor(p2[nt][cc], 32);
            }
        if (q == c4) {
#pragma unroll
            for (int nt = 0; nt < 4; ++nt)
                *(float4*)(part + ((w * 64 + nt * 16 + l15) << 4) + c4 * 4) =
                    make_float4(p2[nt][0], p2[nt][1], p2[nt][2], p2[nt][3]);
        }
    }
    __syncthreads();
    {
        int node = tid >> 2, c4 = (tid & 3) * 4;
        float4 s = make_float4(0.f, 0.f, 0.f, 0.f);
#pragma unroll
        for (int ww = 0; ww < 4; ++ww) {
            float4 v = *(float4*)(part + ((ww * 64 + node) << 4) + c4);
            s.x += v.x; s.y += v.y; s.z += v.z; s.w += v.w;
        }
        float4 bv = *(const float4*)(b2 + c4);
        int grow = row0 + node;
        if (grow < n) {
            float4 hv = make_float4(s.x + bv.x, s.y + bv.y, s.z + bv.z, s.w + bv.w);
            const int half = c4 >> 3;   // classes 0-7 -> A, 8-15 -> B
            const int c    = c4 & 7;
            float* hp = half ? hB : hA;
            float* zp = half ? zsB : zsA;
            *(float4*)(hp + (size_t)grow * 8 + c) = hv;
            float di = dinv[grow];
            *(float4*)(zp + (size_t)grow * 8 + c) =
                make_float4(di * hv.x, di * hv.y, di * hv.z, di * hv.w);
        }
    }
}

// ---------------------------------------------------------------------------
// CSR build
// ---------------------------------------------------------------------------
__global__ void hist_kernel(const int* __restrict__ dst, int* __restrict__ cnt, int e)
{
    int i = blockIdx.x * blockDim.x + threadIdx.x;
    if (i < e) atomicAdd(&cnt[dst[i]], 1);
}

__global__ void dinv_kernel(const int* __restrict__ cnt, float* __restrict__ dinv, int n)
{
    int i = blockIdx.x * blockDim.x + threadIdx.x;
    if (i < n) dinv[i] = rsqrtf((float)cnt[i] + 1.0f);  // +1 self-loop
}

__global__ __launch_bounds__(256) void scan1_kernel(
    const int* __restrict__ cnt, int* __restrict__ row_loc,
    int* __restrict__ bsum, int n)
{
    __shared__ int sm[256];
    int i = blockIdx.x * 256 + threadIdx.x;
    int v = (i < n) ? cnt[i] : 0;
    sm[threadIdx.x] = v;
    __syncthreads();
#pragma unroll
    for (int off = 1; off < 256; off <<= 1) {
        int t = (threadIdx.x >= off) ? sm[threadIdx.x - off] : 0;
        __syncthreads();
        sm[threadIdx.x] += t;
        __syncthreads();
    }
    if (i < n) row_loc[i] = sm[threadIdx.x] - v;
    if (threadIdx.x == 255) bsum[blockIdx.x] = sm[255];
}

__global__ __launch_bounds__(512) void scan2_kernel(
    const int* __restrict__ bsum, int* __restrict__ boff, int nb)
{
    __shared__ int sm[512];
    int i = threadIdx.x;
    int v = (i < nb) ? bsum[i] : 0;
    sm[i] = v;
    __syncthreads();
#pragma unroll
    for (int off = 1; off < 512; off <<= 1) {
        int t = (i >= off) ? sm[i - off] : 0;
        __syncthreads();
        sm[i] += t;
        __syncthreads();
    }
    if (i < nb) boff[i] = sm[i] - v;
}

__global__ void scan3_kernel(int* __restrict__ row_st, const int* __restrict__ boff,
                             int* __restrict__ cursor, int n, int e)
{
    int i = blockIdx.x * blockDim.x + threadIdx.x;
    if (i < n) {
        int r = row_st[i] + boff[i >> 8];
        row_st[i] = r;
        cursor[i] = r;
    }
    if (i == 0) row_st[n] = e;
}

// XCD-windowed scatter (R5 win: WRITE_SIZE 198 -> ~30 MB)
#define SC_CHUNK 2048
__global__ __launch_bounds__(256) void scatter8_kernel(
    const int* __restrict__ src, const int* __restrict__ dst,
    int* __restrict__ cursor, int2* __restrict__ csr_sd, int e)
{
    const int w    = blockIdx.x & 7;
    const int base = (blockIdx.x >> 3) * SC_CHUNK;
    const int wlo  = w * (N_NODES / 8);
    const int whi  = wlo + (N_NODES / 8);
#pragma unroll
    for (int t = 0; t < SC_CHUNK / 256; ++t) {
        int i = base + t * 256 + threadIdx.x;
        if (i < e) {
            int d = dst[i];
            if (d >= wlo && d < whi) {
                int s = src[i];
                int pos = atomicAdd(&cursor[d], 1);
                csr_sd[pos] = make_int2(s, d);
            }
        }
    }
}

// one-time list of nodes whose edge range crosses a 256-edge chunk boundary
// (or deg 0) — the only nodes propA can't finalize in-block.
__global__ void crosslist_kernel(const int* __restrict__ row_st,
                                 int* __restrict__ list, int* __restrict__ cnt, int n)
{
    int i = blockIdx.x * blockDim.x + threadIdx.x;
    if (i < n) {
        int rs = row_st[i], re = row_st[i + 1];
        if (rs == re || (rs >> 8) != ((re - 1) >> 8)) {
            int p = atomicAdd(cnt, 1);
            list[p] = i;
        }
    }
}

// ---------------------------------------------------------------------------
// Propagation with class-halves. half = blockIdx&1 -> (round-robin XCD
// placement) each XCD touches only one 3.2 MB z-half -> fits its 4 MB L2,
// random gathers become L2 hits (R5: 6.4 MB full-width missed to L3/HBM,
// ~110 us/step). 256 edges/chunk, 2 lanes/edge (32 B rows).
// ---------------------------------------------------------------------------
__device__ __forceinline__ void finalize8(
    int d, int half, int h4, float4 S,
    const float* __restrict__ dinv, const float* __restrict__ zin,
    const float* __restrict__ hh, float* __restrict__ zb_out,
    float* __restrict__ zfin, int is_last)
{
    float di = dinv[d];
    const float4 self = *(const float4*)(zin + (size_t)d * 8 + h4);
    const float4 hv   = *(const float4*)(hh  + (size_t)d * 8 + h4);
    float4 zn;
    zn.x = fmaf(1.0f - ALPHA, di * (S.x + self.x), ALPHA * hv.x);
    zn.y = fmaf(1.0f - ALPHA, di * (S.y + self.y), ALPHA * hv.y);
    zn.z = fmaf(1.0f - ALPHA, di * (S.z + self.z), ALPHA * hv.z);
    zn.w = fmaf(1.0f - ALPHA, di * (S.w + self.w), ALPHA * hv.w);
    if (is_last) {
        *(float4*)(zfin + (size_t)d * 16 + half * 8 + h4) = zn;
    } else {
        *(float4*)(zb_out + (size_t)half * HALFN + (size_t)d * 8 + h4) =
            make_float4(di * zn.x, di * zn.y, di * zn.z, di * zn.w);
    }
}

__global__ __launch_bounds__(512) void propA_kernel(
    const int2* __restrict__ csr_sd, const int* __restrict__ row_st,
    const float* __restrict__ dinv, const float* __restrict__ zb_in,
    const float* __restrict__ hAB, float* __restrict__ zb_out,
    float* __restrict__ zfin,
    int* __restrict__ spF_id, int* __restrict__ spB_id,
    float* __restrict__ spF_v, float* __restrict__ spB_v, int is_last)
{
    __shared__ float sc[EB * 8];   // 8 KB
    const int tid  = threadIdx.x;
    const int el   = tid >> 1;            // edge slot 0..255
    const int h4   = (tid & 1) * 4;       // 4-class group within half
    const int half = blockIdx.x & 1;
    const int chunk = blockIdx.x >> 1;
    const int blk_lo = chunk * EB;
    const int j = blk_lo + el;
    const float* zin = zb_in + (size_t)half * HALFN;
    const float* hh  = hAB   + (size_t)half * HALFN;

    const int2 sd = csr_sd[j];
    const int d = sd.y;
    float4 c4 = *(const float4*)(zin + (size_t)sd.x * 8 + h4);
    *(float4*)(sc + el * 8 + h4) = c4;
    __syncthreads();

    const int rs = row_st[d];
    if (el != 0 && j != rs) return;       // not a run start
    const int re = row_st[d + 1];
    const int kend = min(re - blk_lo, EB);
    float4 S = c4;
    for (int k = el + 1; k < kend; ++k) {
        float4 v = *(float4*)(sc + k * 8 + h4);
        S.x += v.x; S.y += v.y; S.z += v.z; S.w += v.w;
    }
    const int run_e = blk_lo + kend;
    const bool full = (j == rs) && (run_e == re);
    if (full)
        finalize8(d, half, h4, S, dinv, zin, hh, zb_out, zfin, is_last);

    const bool first_run = (el == 0);
    const bool last_run  = (kend == EB);
    if (first_run) {
        if (half == 0 && h4 == 0) {
            spF_id[chunk] = full ? -1 : d;
            if (last_run) spB_id[chunk] = -1;
        }
        if (!full) *(float4*)(spF_v + (size_t)half * 100000 + chunk * 8 + h4) = S;
    } else if (last_run) {
        if (half == 0 && h4 == 0) spB_id[chunk] = full ? -1 : d;
        if (!full) *(float4*)(spB_v + (size_t)half * 100000 + chunk * 8 + h4) = S;
    }
}

__global__ __launch_bounds__(256) void propB_kernel(
    const int* __restrict__ cross_list, const int* __restrict__ cross_cnt,
    const int* __restrict__ row_st, const float* __restrict__ dinv,
    const float* __restrict__ zb_in, const float* __restrict__ hAB,
    float* __restrict__ zb_out, float* __restrict__ zfin,
    const int* __restrict__ spF_id, const int* __restrict__ spB_id,
    const float* __restrict__ spF_v, const float* __restrict__ spB_v,
    int is_last)
{
    const int t = blockIdx.x * 256 + threadIdx.x;
    const int idx = t >> 2;
    if (idx >= cross_cnt[0]) return;
    const int d    = cross_list[idx];
    const int half = (t >> 1) & 1;
    const int h4   = (t & 1) * 4;
    const float* zin = zb_in + (size_t)half * HALFN;
    const float* hh  = hAB   + (size_t)half * HALFN;
    const int rs = row_st[d], re = row_st[d + 1];
    float4 S = make_float4(0.f, 0.f, 0.f, 0.f);
    if (re > rs) {
        const int b0 = rs >> 8, b1 = (re - 1) >> 8;
        for (int b = b0; b <= b1; ++b) {
            if (spF_id[b] == d) {
                const float* v = spF_v + (size_t)half * 100000 + b * 8 + h4;
                S.x += v[0]; S.y += v[1]; S.z += v[2]; S.w += v[3];
            }
            if (spB_id[b] == d) {
                const float* v = spB_v + (size_t)half * 100000 + b * 8 + h4;
                S.x += v[0]; S.y += v[1]; S.z += v[2]; S.w += v[3];
            }
        }
    }
    finalize8(d, half, h4, S, dinv, zin, hh, zb_out, zfin, is_last);
}

// final log_softmax over all 16 classes
__global__ __launch_bounds__(256) void lsm_kernel(
    const float* __restrict__ zfin, float* __restrict__ out, int n)
{
    const int g  = blockIdx.x * 64 + (threadIdx.x >> 2);
    const int f4 = (threadIdx.x & 3) * 4;
    if (g >= n) return;
    float4 z = *(const float4*)(zfin + (size_t)g * 16 + f4);
    float m = fmaxf(fmaxf(z.x, z.y), fmaxf(z.z, z.w));
    m = fmaxf(m, __shfl_xor(m, 1));
    m = fmaxf(m, __shfl_xor(m, 2));
    float ss = expf(z.x - m) + expf(z.y - m) + expf(z.z - m) + expf(z.w - m);
    ss += __shfl_xor(ss, 1);
    ss += __shfl_xor(ss, 2);
    float ls = logf(ss);
    *(float4*)(out + (size_t)g * 16 + f4) =
        make_float4(z.x - m - ls, z.y - m - ls, z.z - m - ls, z.w - m - ls);
}

// ---------------------------------------------------------------------------
extern "C" void kernel_launch(void* const* d_in, const int* in_sizes, int n_in,
                              void* d_out, int out_size, void* d_ws, size_t ws_size,
                              hipStream_t stream)
{
    const float* x  = (const float*)d_in[0];
    const float* W1 = (const float*)d_in[1];
    const float* b1 = (const float*)d_in[2];
    const float* W2 = (const float*)d_in[3];
    const float* b2 = (const float*)d_in[4];
    const int*   ei = (const int*)d_in[5];

    const int N = N_NODES;
    const int E = N_EDGES;
    const int* srcp = ei;
    const int* dstp = ei + E;

    float* ws = (float*)d_ws;
    float* hA      = ws;                        // 800,000
    float* hB      = ws + 800000;               // 800,000
    float* Zbase   = ws + 1600000;              // Zb0: [half][N*8] = 1.6M ; Zb1: +1.6M
    float* dinv    = ws + 4800000;              // 100,000
    int*   row_st  = (int*)(ws + 4900000);      // 100,001 (pad 100004)
    int2*  csr_sd  = (int2*)(ws + 5000004);     // 3.2M x 8B
    int*   spF_id  = (int*)(ws + 11400004);     // 12,500
    int*   spB_id  = (int*)(ws + 11412504);     // 12,500
    float* spF_v   = ws + 11425004;             // 200,000 ([2][12500*8])
    float* spB_v   = ws + 11625004;             // 200,000
    int*   c_list  = (int*)(ws + 11825004);     // 131,072
    int*   c_cnt   = (int*)(ws + 11956076);     // 1     -> end ~47.8 MB
    // transient overlays (dead before hosts written):
    int*   cnt     = (int*)(ws);                // in hA
    int*   cursor  = (int*)(ws + 100000);       // in hA
    int*   bsum    = (int*)(ws + 200000);       // in hA (512)
    int*   boff    = (int*)(ws + 200512);       // in hA (512)
    uint4* W1f     = (uint4*)(ws + 3200000);    // in Zb1 (first written at k=0)
    float* zfin    = Zbase;                     // Zb0 region; dead at k=9 (zin=Zb1)

    const int NB_SCAN = (N + 255) / 256;        // 391

    hipMemsetAsync(cnt, 0, (size_t)N * sizeof(int), stream);
    hipMemsetAsync(c_cnt, 0, sizeof(int), stream);
    hist_kernel<<<(E + 255) / 256, 256, 0, stream>>>(dstp, cnt, E);
    dinv_kernel<<<(N + 255) / 256, 256, 0, stream>>>(cnt, dinv, N);
    scan1_kernel<<<NB_SCAN, 256, 0, stream>>>(cnt, row_st, bsum, N);
    scan2_kernel<<<1, 512, 0, stream>>>(bsum, boff, NB_SCAN);
    scan3_kernel<<<(N + 255) / 256, 256, 0, stream>>>(row_st, boff, cursor, N, E);
    {
        const int nchunks = (E + SC_CHUNK - 1) / SC_CHUNK;
        scatter8_kernel<<<nchunks * 8, 256, 0, stream>>>(srcp, dstp, cursor, csr_sd, E);
    }
    crosslist_kernel<<<(N + 255) / 256, 256, 0, stream>>>(row_st, c_list, c_cnt, N);
    w1_frag_kernel<<<64, 256, 0, stream>>>(W1, W1f);
    mlp_kernel<<<(N + 63) / 64, 256, 0, stream>>>(x, W1f, b1, W2, b2, dinv,
                                                  hA, hB, Zbase, Zbase + HALFN, N);

    for (int k = 0; k < 10; ++k) {
        const int last = (k == 9) ? 1 : 0;
        const float* zbin = Zbase + (size_t)(k & 1) * 1600000;
        float* zbout      = Zbase + (size_t)(1 - (k & 1)) * 1600000;
        propA_kernel<<<NCHUNK * 2, 512, 0, stream>>>(csr_sd, row_st, dinv, zbin, hA,
                                                     zbout, zfin, spF_id, spB_id,
                                                     spF_v, spB_v, last);
        propB_kernel<<<2048, 256, 0, stream>>>(c_list, c_cnt, row_st, dinv, zbin, hA,
                                               zbout, zfin, spF_id, spB_id,
                                               spF_v, spB_v, last);
    }
    lsm_kernel<<<(N + 63) / 64, 256, 0, stream>>>(zfin, (float*)d_out, N);
}

// Round 8
// 1650.125 us; speedup vs baseline: 1.2034x; 1.2034x over previous
//
#include <hip/hip_runtime.h>
#include <hip/hip_bf16.h>
#include <stdint.h>

#define N_NODES 100000
#define N_EDGES 3200000
#define ALPHA   0.1f
#define EB      128              // edges per propA chunk
#define NCHUNK  (N_EDGES / EB)   // 25000
#define HALFN   800000           // N * 8 floats per class-half

typedef __attribute__((ext_vector_type(8))) short v8s;   // 8 x bf16
typedef __attribute__((ext_vector_type(4))) float f32x4; // MFMA acc

__device__ __forceinline__ uint32_t bf16_rne(float f) {
    uint32_t u = __float_as_uint(f);
    return (u + 0x7FFFu + ((u >> 16) & 1u)) >> 16;
}
__device__ __forceinline__ float bf16_f32(uint32_t b) { return __uint_as_float(b << 16); }

// ---------------------------------------------------------------------------
// W1 [256][512] fp32 -> A-fragment-ordered hi/lo bf16 chunks in global.
// ---------------------------------------------------------------------------
__global__ __launch_bounds__(256) void w1_frag_kernel(
    const float* __restrict__ W1, uint4* __restrict__ W1f)
{
    int tid = blockIdx.x * 256 + threadIdx.x;   // 16384
    int ks = tid >> 10, T = (tid >> 6) & 15, l = tid & 63;
    int row = T * 16 + (l & 15);
    int kb  = ks * 32 + (l >> 4) * 8;
    const float* src = W1 + (size_t)row * 512 + kb;
    float4 f0 = *(const float4*)(src);
    float4 f1 = *(const float4*)(src + 4);
    float f[8] = {f0.x, f0.y, f0.z, f0.w, f1.x, f1.y, f1.z, f1.w};
    uint32_t hi[8], lo[8];
#pragma unroll
    for (int j = 0; j < 8; ++j) {
        hi[j] = bf16_rne(f[j]);
        lo[j] = bf16_rne(f[j] - bf16_f32(hi[j]));
    }
    uint4 H = make_uint4(hi[0] | (hi[1] << 16), hi[2] | (hi[3] << 16),
                         hi[4] | (hi[5] << 16), hi[6] | (hi[7] << 16));
    uint4 L = make_uint4(lo[0] | (lo[1] << 16), lo[2] | (lo[3] << 16),
                         lo[4] | (lo[5] << 16), lo[6] | (lo[7] << 16));
    size_t base = ((size_t)(ks * 2) * 16 + T) * 64 + l;
    W1f[base]        = H;
    W1f[base + 1024] = L;   // p=1 plane
}

// ---------------------------------------------------------------------------
// MLP via MFMA bf16 hi/lo split — R5's EXACT two-barrier K-loop (absmax-
// clean at 0.046875; R7's pipelined variant is the bisect suspect for the
// 0.078 accuracy failure). Epilogue writes class-half arrays hA/hB + zsA/zsB.
// bound (256,2): VGPR>=116 needed; (256,4) forced 64 VGPRs -> spill (R6).
// ---------------------------------------------------------------------------
__global__ __launch_bounds__(256, 2) void mlp_kernel(
    const float* __restrict__ x, const uint4* __restrict__ W1f,
    const float* __restrict__ b1, const float* __restrict__ W2,
    const float* __restrict__ b2, const float* __restrict__ dinv,
    float* __restrict__ hA, float* __restrict__ hB,
    float* __restrict__ zsA, float* __restrict__ zsB, int n)
{
    __shared__ __align__(16) char smem[33280];
    char*  xs   = smem;                    // K-loop: hi plane 4096 + lo plane 4096
    float* W2s  = (float*)smem;            // epilogue overlay: [16][260]
    float* part = (float*)(smem + 16640);  // epilogue overlay: [4][64][16]

    const int tid = threadIdx.x;
    const int w = tid >> 6, l = tid & 63;
    const int l15 = l & 15, q = l >> 4;
    const int row0 = blockIdx.x * 64;

    const int s_l15 = tid & 15;
    const int s_seg = (tid >> 4) & 3;
    const int s_u   = tid >> 6;
    const int s_grow = row0 + s_u * 16 + s_l15;
    const int s_off  = s_u * 1024 + (s_seg * 16 + s_l15) * 16;

    f32x4 acc[4][4];
#pragma unroll
    for (int mt = 0; mt < 4; ++mt)
#pragma unroll
        for (int nt = 0; nt < 4; ++nt) acc[mt][nt] = (f32x4){0.f, 0.f, 0.f, 0.f};

    for (int ks = 0; ks < 16; ++ks) {
        uint4 aHu[4], aLu[4];
#pragma unroll
        for (int mt = 0; mt < 4; ++mt) {
            size_t cidx = ((size_t)(ks * 2) * 16 + (w * 4 + mt)) * 64 + l;
            aHu[mt] = W1f[cidx];
            aLu[mt] = W1f[cidx + 1024];
        }
        float4 f0 = make_float4(0.f, 0.f, 0.f, 0.f), f1 = f0;
        if (s_grow < n) {
            const float* xp = x + (size_t)s_grow * 512 + ks * 32 + s_seg * 8;
            f0 = *(const float4*)(xp);
            f1 = *(const float4*)(xp + 4);
        }
        float f[8] = {f0.x, f0.y, f0.z, f0.w, f1.x, f1.y, f1.z, f1.w};
        uint32_t hi[8], lo[8];
#pragma unroll
        for (int j = 0; j < 8; ++j) {
            hi[j] = bf16_rne(f[j]);
            lo[j] = bf16_rne(f[j] - bf16_f32(hi[j]));
        }
        uint4 H = make_uint4(hi[0] | (hi[1] << 16), hi[2] | (hi[3] << 16),
                             hi[4] | (hi[5] << 16), hi[6] | (hi[7] << 16));
        uint4 L = make_uint4(lo[0] | (lo[1] << 16), lo[2] | (lo[3] << 16),
                             lo[4] | (lo[5] << 16), lo[6] | (lo[7] << 16));
        __syncthreads();
        *(uint4*)(xs + s_off)        = H;
        *(uint4*)(xs + 4096 + s_off) = L;
        __syncthreads();

        v8s bH[4], bL[4];
#pragma unroll
        for (int nt = 0; nt < 4; ++nt) {
            bH[nt] = *(v8s*)(xs +        nt * 1024 + l * 16);
            bL[nt] = *(v8s*)(xs + 4096 + nt * 1024 + l * 16);
        }
#pragma unroll
        for (int mt = 0; mt < 4; ++mt) {
            v8s aH = *(v8s*)&aHu[mt];
            v8s aL = *(v8s*)&aLu[mt];
#pragma unroll
            for (int nt = 0; nt < 4; ++nt) {
                f32x4 c = acc[mt][nt];
                c = __builtin_amdgcn_mfma_f32_16x16x32_bf16(aH, bH[nt], c, 0, 0, 0);
                c = __builtin_amdgcn_mfma_f32_16x16x32_bf16(aH, bL[nt], c, 0, 0, 0);
                c = __builtin_amdgcn_mfma_f32_16x16x32_bf16(aL, bH[nt], c, 0, 0, 0);
                acc[mt][nt] = c;
            }
        }
    }

    // ---- bias + relu ----
#pragma unroll
    for (int mt = 0; mt < 4; ++mt) {
        float4 bv = *(const float4*)(b1 + w * 64 + mt * 16 + q * 4);
#pragma unroll
        for (int nt = 0; nt < 4; ++nt) {
            acc[mt][nt][0] = fmaxf(acc[mt][nt][0] + bv.x, 0.f);
            acc[mt][nt][1] = fmaxf(acc[mt][nt][1] + bv.y, 0.f);
            acc[mt][nt][2] = fmaxf(acc[mt][nt][2] + bv.z, 0.f);
            acc[mt][nt][3] = fmaxf(acc[mt][nt][3] + bv.w, 0.f);
        }
    }

    __syncthreads();
    {
        int c = tid >> 4, k16 = (tid & 15) * 16;
#pragma unroll
        for (int i = 0; i < 4; ++i)
            *(float4*)(W2s + c * 260 + k16 + i * 4) =
                *(const float4*)(W2 + c * 256 + k16 + i * 4);
    }
    __syncthreads();

    // ---- GEMM2, 4-class chunks (16 live floats; 64 spilled in R3) ----
#pragma unroll
    for (int c4 = 0; c4 < 4; ++c4) {
        float p2[4][4];
#pragma unroll
        for (int nt = 0; nt < 4; ++nt)
#pragma unroll
            for (int cc = 0; cc < 4; ++cc) p2[nt][cc] = 0.f;
#pragma unroll
        for (int mt = 0; mt < 4; ++mt)
#pragma unroll
            for (int cc = 0; cc < 4; ++cc) {
                float4 wv = *(float4*)(W2s + (c4 * 4 + cc) * 260 + w * 64 + mt * 16 + q * 4);
#pragma unroll
                for (int nt = 0; nt < 4; ++nt)
                    p2[nt][cc] += acc[mt][nt][0] * wv.x + acc[mt][nt][1] * wv.y +
                                  acc[mt][nt][2] * wv.z + acc[mt][nt][3] * wv.w;
            }
#pragma unroll
        for (int nt = 0; nt < 4; ++nt)
#pragma unroll
            for (int cc = 0; cc < 4; ++cc) {
                p2[nt][cc] += __shfl_xor(p2[nt][cc], 16);
                p2[nt][cc] += __shfl_xor(p2[nt][cc], 32);
            }
        if (q == c4) {
#pragma unroll
            for (int nt = 0; nt < 4; ++nt)
                *(float4*)(part + ((w * 64 + nt * 16 + l15) << 4) + c4 * 4) =
                    make_float4(p2[nt][0], p2[nt][1], p2[nt][2], p2[nt][3]);
        }
    }
    __syncthreads();
    {
        int node = tid >> 2, c4 = (tid & 3) * 4;
        float4 s = make_float4(0.f, 0.f, 0.f, 0.f);
#pragma unroll
        for (int ww = 0; ww < 4; ++ww) {
            float4 v = *(float4*)(part + ((ww * 64 + node) << 4) + c4);
            s.x += v.x; s.y += v.y; s.z += v.z; s.w += v.w;
        }
        float4 bv = *(const float4*)(b2 + c4);
        int grow = row0 + node;
        if (grow < n) {
            float4 hv = make_float4(s.x + bv.x, s.y + bv.y, s.z + bv.z, s.w + bv.w);
            const int half = c4 >> 3;
            const int c    = c4 & 7;
            float* hp = half ? hB : hA;
            float* zp = half ? zsB : zsA;
            *(float4*)(hp + (size_t)grow * 8 + c) = hv;
            float di = dinv[grow];
            *(float4*)(zp + (size_t)grow * 8 + c) =
                make_float4(di * hv.x, di * hv.y, di * hv.z, di * hv.w);
        }
    }
}

// ---------------------------------------------------------------------------
// CSR build
// ---------------------------------------------------------------------------
__global__ void hist_kernel(const int* __restrict__ dst, int* __restrict__ cnt, int e)
{
    int i = blockIdx.x * blockDim.x + threadIdx.x;
    if (i < e) atomicAdd(&cnt[dst[i]], 1);
}

__global__ void dinv_kernel(const int* __restrict__ cnt, float* __restrict__ dinv, int n)
{
    int i = blockIdx.x * blockDim.x + threadIdx.x;
    if (i < n) dinv[i] = rsqrtf((float)cnt[i] + 1.0f);
}

__global__ __launch_bounds__(256) void scan1_kernel(
    const int* __restrict__ cnt, int* __restrict__ row_loc,
    int* __restrict__ bsum, int n)
{
    __shared__ int sm[256];
    int i = blockIdx.x * 256 + threadIdx.x;
    int v = (i < n) ? cnt[i] : 0;
    sm[threadIdx.x] = v;
    __syncthreads();
#pragma unroll
    for (int off = 1; off < 256; off <<= 1) {
        int t = (threadIdx.x >= off) ? sm[threadIdx.x - off] : 0;
        __syncthreads();
        sm[threadIdx.x] += t;
        __syncthreads();
    }
    if (i < n) row_loc[i] = sm[threadIdx.x] - v;
    if (threadIdx.x == 255) bsum[blockIdx.x] = sm[255];
}

__global__ __launch_bounds__(512) void scan2_kernel(
    const int* __restrict__ bsum, int* __restrict__ boff, int nb)
{
    __shared__ int sm[512];
    int i = threadIdx.x;
    int v = (i < nb) ? bsum[i] : 0;
    sm[i] = v;
    __syncthreads();
#pragma unroll
    for (int off = 1; off < 512; off <<= 1) {
        int t = (i >= off) ? sm[i - off] : 0;
        __syncthreads();
        sm[i] += t;
        __syncthreads();
    }
    if (i < nb) boff[i] = sm[i] - v;
}

__global__ void scan3_kernel(int* __restrict__ row_st, const int* __restrict__ boff,
                             int* __restrict__ cursor, int n, int e)
{
    int i = blockIdx.x * blockDim.x + threadIdx.x;
    if (i < n) {
        int r = row_st[i] + boff[i >> 8];
        row_st[i] = r;
        cursor[i] = r;
    }
    if (i == 0) row_st[n] = e;
}

// XCD-windowed scatter (R5 win)
#define SC_CHUNK 2048
__global__ __launch_bounds__(256) void scatter8_kernel(
    const int* __restrict__ src, const int* __restrict__ dst,
    int* __restrict__ cursor, int2* __restrict__ csr_sd, int e)
{
    const int w    = blockIdx.x & 7;
    const int base = (blockIdx.x >> 3) * SC_CHUNK;
    const int wlo  = w * (N_NODES / 8);
    const int whi  = wlo + (N_NODES / 8);
#pragma unroll
    for (int t = 0; t < SC_CHUNK / 256; ++t) {
        int i = base + t * 256 + threadIdx.x;
        if (i < e) {
            int d = dst[i];
            if (d >= wlo && d < whi) {
                int s = src[i];
                int pos = atomicAdd(&cursor[d], 1);
                csr_sd[pos] = make_int2(s, d);
            }
        }
    }
}

// one-time list of nodes whose edge range crosses a 128-edge chunk boundary
__global__ void crosslist_kernel(const int* __restrict__ row_st,
                                 int* __restrict__ list, int* __restrict__ cnt, int n)
{
    int i = blockIdx.x * blockDim.x + threadIdx.x;
    if (i < n) {
        int rs = row_st[i], re = row_st[i + 1];
        if (rs == re || (rs >> 7) != ((re - 1) >> 7)) {
            int p = atomicAdd(cnt, 1);
            list[p] = i;
        }
    }
}

// ---------------------------------------------------------------------------
// Propagation. Class-halves in SEQUENTIAL dispatches (3.2 MB hot gather set
// per dispatch fits any XCD's 4 MB L2 regardless of block->XCD mapping).
// EB=128. zs = dinv*z flows between steps.
// ---------------------------------------------------------------------------
__device__ __forceinline__ void finalize8(
    int d, int half, int h4, float4 S,
    const float* __restrict__ dinv, const float* __restrict__ zin,
    const float* __restrict__ hh, float* __restrict__ zout,
    float* __restrict__ zfin, int is_last)
{
    float di = dinv[d];
    const float4 self = *(const float4*)(zin + (size_t)d * 8 + h4);
    const float4 hv   = *(const float4*)(hh  + (size_t)d * 8 + h4);
    float4 zn;
    zn.x = fmaf(1.0f - ALPHA, di * (S.x + self.x), ALPHA * hv.x);
    zn.y = fmaf(1.0f - ALPHA, di * (S.y + self.y), ALPHA * hv.y);
    zn.z = fmaf(1.0f - ALPHA, di * (S.z + self.z), ALPHA * hv.z);
    zn.w = fmaf(1.0f - ALPHA, di * (S.w + self.w), ALPHA * hv.w);
    if (is_last) {
        *(float4*)(zfin + (size_t)d * 16 + half * 8 + h4) = zn;
    } else {
        *(float4*)(zout + (size_t)d * 8 + h4) =
            make_float4(di * zn.x, di * zn.y, di * zn.z, di * zn.w);
    }
}

__global__ __launch_bounds__(256) void propA_kernel(
    const int2* __restrict__ csr_sd, const int* __restrict__ row_st,
    const float* __restrict__ dinv, const float* __restrict__ zin,
    const float* __restrict__ hh, float* __restrict__ zout,
    float* __restrict__ zfin,
    int* __restrict__ spF_id, int* __restrict__ spB_id,
    float* __restrict__ spF_v, float* __restrict__ spB_v,
    int half, int is_last)
{
    __shared__ float sc[EB * 8];   // 4 KB
    const int tid = threadIdx.x;
    const int el  = tid >> 1;            // edge slot 0..127
    const int h4  = (tid & 1) * 4;
    const int chunk = blockIdx.x;
    const int blk_lo = chunk * EB;
    const int j = blk_lo + el;

    const int2 sd = csr_sd[j];
    const int d = sd.y;
    float4 c4 = *(const float4*)(zin + (size_t)sd.x * 8 + h4);
    *(float4*)(sc + el * 8 + h4) = c4;
    __syncthreads();

    const int rs = row_st[d];
    if (el != 0 && j != rs) return;
    const int re = row_st[d + 1];
    const int kend = min(re - blk_lo, EB);
    float4 S = c4;
    for (int k = el + 1; k < kend; ++k) {
        float4 v = *(float4*)(sc + k * 8 + h4);
        S.x += v.x; S.y += v.y; S.z += v.z; S.w += v.w;
    }
    const int run_e = blk_lo + kend;
    const bool full = (j == rs) && (run_e == re);
    if (full)
        finalize8(d, half, h4, S, dinv, zin, hh, zout, zfin, is_last);

    const bool first_run = (el == 0);
    const bool last_run  = (kend == EB);
    if (first_run) {
        if (half == 0 && h4 == 0) {
            spF_id[chunk] = full ? -1 : d;
            if (last_run) spB_id[chunk] = -1;
        }
        if (!full) *(float4*)(spF_v + (size_t)half * (NCHUNK * 8) + chunk * 8 + h4) = S;
    } else if (last_run) {
        if (half == 0 && h4 == 0) spB_id[chunk] = full ? -1 : d;
        if (!full) *(float4*)(spB_v + (size_t)half * (NCHUNK * 8) + chunk * 8 + h4) = S;
    }
}

__global__ __launch_bounds__(256) void propB_kernel(
    const int* __restrict__ cross_list, const int* __restrict__ cross_cnt,
    const int* __restrict__ row_st, const float* __restrict__ dinv,
    const float* __restrict__ zb_in, const float* __restrict__ hAB,
    float* __restrict__ zb_out, float* __restrict__ zfin,
    const int* __restrict__ spF_id, const int* __restrict__ spB_id,
    const float* __restrict__ spF_v, const float* __restrict__ spB_v,
    int is_last)
{
    const int t = blockIdx.x * 256 + threadIdx.x;
    const int idx = t >> 2;
    if (idx >= cross_cnt[0]) return;
    const int d    = cross_list[idx];
    const int half = (t >> 1) & 1;
    const int h4   = (t & 1) * 4;
    const float* zin = zb_in + (size_t)half * HALFN;
    const float* hh  = hAB   + (size_t)half * HALFN;
    float* zout      = zb_out + (size_t)half * HALFN;
    const int rs = row_st[d], re = row_st[d + 1];
    float4 S = make_float4(0.f, 0.f, 0.f, 0.f);
    if (re > rs) {
        const int b0 = rs >> 7, b1 = (re - 1) >> 7;
        for (int b = b0; b <= b1; ++b) {
            if (spF_id[b] == d) {
                const float* v = spF_v + (size_t)half * (NCHUNK * 8) + b * 8 + h4;
                S.x += v[0]; S.y += v[1]; S.z += v[2]; S.w += v[3];
            }
            if (spB_id[b] == d) {
                const float* v = spB_v + (size_t)half * (NCHUNK * 8) + b * 8 + h4;
                S.x += v[0]; S.y += v[1]; S.z += v[2]; S.w += v[3];
            }
        }
    }
    finalize8(d, half, h4, S, dinv, zin, hh, zout, zfin, is_last);
}

// final log_softmax over 16 classes
__global__ __launch_bounds__(256) void lsm_kernel(
    const float* __restrict__ zfin, float* __restrict__ out, int n)
{
    const int g  = blockIdx.x * 64 + (threadIdx.x >> 2);
    const int f4 = (threadIdx.x & 3) * 4;
    if (g >= n) return;
    float4 z = *(const float4*)(zfin + (size_t)g * 16 + f4);
    float m = fmaxf(fmaxf(z.x, z.y), fmaxf(z.z, z.w));
    m = fmaxf(m, __shfl_xor(m, 1));
    m = fmaxf(m, __shfl_xor(m, 2));
    float ss = expf(z.x - m) + expf(z.y - m) + expf(z.z - m) + expf(z.w - m);
    ss += __shfl_xor(ss, 1);
    ss += __shfl_xor(ss, 2);
    float ls = logf(ss);
    *(float4*)(out + (size_t)g * 16 + f4) =
        make_float4(z.x - m - ls, z.y - m - ls, z.z - m - ls, z.w - m - ls);
}

// ---------------------------------------------------------------------------
extern "C" void kernel_launch(void* const* d_in, const int* in_sizes, int n_in,
                              void* d_out, int out_size, void* d_ws, size_t ws_size,
                              hipStream_t stream)
{
    const float* x  = (const float*)d_in[0];
    const float* W1 = (const float*)d_in[1];
    const float* b1 = (const float*)d_in[2];
    const float* W2 = (const float*)d_in[3];
    const float* b2 = (const float*)d_in[4];
    const int*   ei = (const int*)d_in[5];

    const int N = N_NODES;
    const int E = N_EDGES;
    const int* srcp = ei;
    const int* dstp = ei + E;

    float* ws = (float*)d_ws;
    float* hA      = ws;                        // 800,000
    float* hB      = ws + 800000;               // 800,000
    float* Zbase   = ws + 1600000;              // Zb0 / Zb1, 1.6M floats each
    float* dinv    = ws + 4800000;              // 100,000
    int*   row_st  = (int*)(ws + 4900000);      // 100,001 (pad 100004)
    int2*  csr_sd  = (int2*)(ws + 5000004);     // 3.2M x 8B
    int*   spF_id  = (int*)(ws + 11400004);     // 25,000
    int*   spB_id  = (int*)(ws + 11425004);     // 25,000
    float* spF_v   = ws + 11450004;             // 400,000 ([2][25000*8])
    float* spB_v   = ws + 11850004;             // 400,000
    int*   c_list  = (int*)(ws + 12250004);     // 100,000
    int*   c_cnt   = (int*)(ws + 12350004);     // 1
    // transient overlays:
    int*   cnt     = (int*)(ws);                // in hA
    int*   cursor  = (int*)(ws + 100000);       // in hA
    int*   bsum    = (int*)(ws + 200000);       // in hA (512)
    int*   boff    = (int*)(ws + 200512);       // in hA (512)
    uint4* W1f     = (uint4*)(ws + 3200000);    // in Zb1 (dead before step 0 writes it)
    float* zfin    = Zbase;                     // Zb0; free at k=9 (zin = Zb1)

    const int NB_SCAN = (N + 255) / 256;

    hipMemsetAsync(cnt, 0, (size_t)N * sizeof(int), stream);
    hipMemsetAsync(c_cnt, 0, sizeof(int), stream);
    hist_kernel<<<(E + 255) / 256, 256, 0, stream>>>(dstp, cnt, E);
    dinv_kernel<<<(N + 255) / 256, 256, 0, stream>>>(cnt, dinv, N);
    scan1_kernel<<<NB_SCAN, 256, 0, stream>>>(cnt, row_st, bsum, N);
    scan2_kernel<<<1, 512, 0, stream>>>(bsum, boff, NB_SCAN);
    scan3_kernel<<<(N + 255) / 256, 256, 0, stream>>>(row_st, boff, cursor, N, E);
    {
        const int nchunks = (E + SC_CHUNK - 1) / SC_CHUNK;
        scatter8_kernel<<<nchunks * 8, 256, 0, stream>>>(srcp, dstp, cursor, csr_sd, E);
    }
    crosslist_kernel<<<(N + 255) / 256, 256, 0, stream>>>(row_st, c_list, c_cnt, N);
    w1_frag_kernel<<<64, 256, 0, stream>>>(W1, W1f);
    mlp_kernel<<<(N + 63) / 64, 256, 0, stream>>>(x, W1f, b1, W2, b2, dinv,
                                                  hA, hB, Zbase, Zbase + HALFN, N);

    for (int k = 0; k < 10; ++k) {
        const int last = (k == 9) ? 1 : 0;
        const float* zbin = Zbase + (size_t)(k & 1) * 1600000;
        float* zbout      = Zbase + (size_t)(1 - (k & 1)) * 1600000;
        for (int half = 0; half < 2; ++half) {
            propA_kernel<<<NCHUNK, 256, 0, stream>>>(
                csr_sd, row_st, dinv,
                zbin + (size_t)half * HALFN,
                (half ? hB : hA),
                zbout + (size_t)half * HALFN,
                zfin, spF_id, spB_id, spF_v, spB_v, half, last);
        }
        propB_kernel<<<512, 256, 0, stream>>>(c_list, c_cnt, row_st, dinv, zbin, hA,
                                              zbout, zfin, spF_id, spB_id,
                                              spF_v, spB_v, last);
    }
    lsm_kernel<<<(N + 63) / 64, 256, 0, stream>>>(zfin, (float*)d_out, N);
}